// Round 5
// baseline (379.817 us; speedup 1.0000x reference)
//
#include <hip/hip_runtime.h>

// MakeCutouts: out[(n*B+b), c, i, j] = x[b, c, oy[n] + i*sz[n]/224, ox[n] + j*sz[n]/224]
// B=16, C=3, H=W=512, CUTN=32, CUT_SIZE=224. Output fp32, 308 MB.
//
// v5: persistent wave-workers + dynamic row queue (fixes v4's load imbalance).
// v4 (static (img,16-row-slice) blocks, grid ~= residency) ran ~156us vs the
// 57us traffic floor: middle slices are covered by ~all 32 cutouts, edge
// slices by few -> slowest block ~2x average sets the runtime. Now: task =
// (img, input row y), 24576 tasks drained dynamically by 8192 persistent
// waves. Stage the 2KB row into a PRIVATE per-wave LDS slot (no barriers),
// scan the 32 cutouts (wave-uniform scalar math, sz>=224 => each input row
// feeds <=1 output row per cutout), gather+store. Read-once preserved.
// Tail self-balances: task progress is store-backpressure-bound, and the
// last waves get the full write BW.
//
// 8 queue counters (one per XCD via bid&7, 128B apart) kill same-line atomic
// serialization; partition p owns images {6p..6p+5} -> partitions are EXACTLY
// equal (every image emits 32*224 output rows) and get L2 image affinity.

#define CUT_SIZE 224
#define CUTN     32
#define BATCH    16
#define CHAN     3
#define HEIGHT   512
#define WIDTH    512
#define NIMG     (BATCH * CHAN)          // 48
#define WPB      4                        // waves per block
#define NPART    8                        // queue partitions (= XCDs)
#define IMG_PER_PART   (NIMG / NPART)     // 6
#define TASKS_PER_PART (IMG_PER_PART * HEIGHT)  // 3072

typedef const __attribute__((address_space(1))) void* gas_ptr;
typedef __attribute__((address_space(3))) void*       las_ptr;

__device__ __forceinline__ void stage_row(const float* src_row, float* lds_buf, int lane)
{
    // Stage 2048 B (one full input row): 2 x (64 lanes x 16 B).
    // LDS dest is wave-uniform base + lane*16 (HW rule); global src is per-lane.
    __builtin_amdgcn_global_load_lds((gas_ptr)(src_row + lane * 4),
                                     (las_ptr)(lds_buf), 16, 0, 0);
    __builtin_amdgcn_global_load_lds((gas_ptr)(src_row + 256 + lane * 4),
                                     (las_ptr)(lds_buf + 256), 16, 0, 0);
}

__global__ __launch_bounds__(256) void make_cutouts_kernel(
    const float* __restrict__ x,
    const int*   __restrict__ sizes,
    const int*   __restrict__ offsetx,
    const int*   __restrict__ offsety,
    float*       __restrict__ out,
    int*         __restrict__ counters)
{
    __shared__ __align__(16) float lds[WPB][WIDTH];   // 8 KB/block

    const int wid  = threadIdx.x >> 6;
    const int lane = threadIdx.x & 63;

    const int p   = blockIdx.x & (NPART - 1);     // dispatch round-robins over XCDs
    int* ctr = counters + p * 32;                 // 128B-separated counters

    float* myl = &lds[wid][0];

    for (;;) {
        int t;
        if (lane == 0) t = atomicAdd(ctr, 1);
        t = __builtin_amdgcn_readfirstlane(t);    // all lanes active; lane 0 is first
        if (t >= TASKS_PER_PART) break;

        const int img = p * IMG_PER_PART + (t >> 9);  // 0..47
        const int y   = t & (HEIGHT - 1);             // 0..511

        stage_row(x + ((size_t)img * HEIGHT + y) * WIDTH, myl, lane);
        asm volatile("s_waitcnt vmcnt(0)" ::: "memory");
        __builtin_amdgcn_sched_barrier(0);

        const int b = img / CHAN;
        const int c = img % CHAN;

        for (int n = 0; n < CUTN; ++n) {
            const int      sz  = sizes[n];
            const unsigned usz = (unsigned)sz;
            const unsigned ud  = (unsigned)(y - offsety[n]);
            if (ud >= usz) continue;              // row not inside cutout's y-span

            // Smallest i with floor(i*sz/224) >= d; row used iff equality holds.
            unsigned i = (ud * 224u + usz - 1u) / usz;
            if (i >= 224u) continue;
            if ((i * usz) / 224u != ud) continue; // this input row is skipped

            const int ox  = offsetx[n];
            const int xi0 = ox + (int)(((unsigned)(lane      ) * usz) / 224u);
            const int xi1 = ox + (int)(((unsigned)(lane +  64) * usz) / 224u);
            const int xi2 = ox + (int)(((unsigned)(lane + 128) * usz) / 224u);
            const int xi3 = (lane < 32)
                          ? ox + (int)(((unsigned)(lane + 192) * usz) / 224u)
                          : xi0;                  // clamped; unused for lane>=32

            const float v0 = myl[xi0];
            const float v1 = myl[xi1];
            const float v2 = myl[xi2];
            const float v3 = myl[xi3];

            float* orow = out + (size_t)((n * BATCH + b) * CHAN + c)
                                  * (CUT_SIZE * CUT_SIZE)
                              + (size_t)i * CUT_SIZE;
            orow[lane      ] = v0;
            orow[lane +  64] = v1;
            orow[lane + 128] = v2;
            if (lane < 32) orow[lane + 192] = v3;
        }

        // Gathers must complete before the next task's DMA overwrites myl.
        asm volatile("s_waitcnt lgkmcnt(0)" ::: "memory");
        __builtin_amdgcn_sched_barrier(0);
    }
}

extern "C" void kernel_launch(void* const* d_in, const int* in_sizes, int n_in,
                              void* d_out, int out_size, void* d_ws, size_t ws_size,
                              hipStream_t stream) {
    const float* x       = (const float*)d_in[0];
    const int*   sizes   = (const int*)d_in[1];
    const int*   offsetx = (const int*)d_in[2];
    const int*   offsety = (const int*)d_in[3];
    float*       out     = (float*)d_out;
    int*         counters = (int*)d_ws;

    hipMemsetAsync(d_ws, 0, NPART * 32 * sizeof(int), stream);

    const int grid = 2048;   // persistent: ~8 blocks/CU; extras drain and exit
    make_cutouts_kernel<<<grid, 256, 0, stream>>>(x, sizes, offsetx, offsety,
                                                  out, counters);
}